// Round 10
// baseline (284.900 us; speedup 1.0000x reference)
//
#include <hip/hip_runtime.h>
#include <math.h>

#define NB   4
#define LQ   5448
#define LSP  5440
#define NR   21792   // NB * LQ
#define DM   256

typedef unsigned short u16;
typedef __attribute__((ext_vector_type(8))) short short8;   // 8 bf16 (4 VGPR)
typedef __attribute__((ext_vector_type(4))) float f32x4;    // MFMA acc
typedef __attribute__((ext_vector_type(4))) unsigned int uint4v; // 16B move

__device__ __forceinline__ u16 f2bf(float f) {
  unsigned int u = __float_as_uint(f);
  u = (u + 0x7fff + ((u >> 16) & 1)) >> 16;   // RNE
  return (u16)u;
}
__device__ __forceinline__ float bf2f(u16 u) {
  return __uint_as_float(((unsigned int)u) << 16);
}
__device__ __forceinline__ uint4v pack8(float4 a, float4 b) {
  uint4v r;
  r.x = (unsigned)f2bf(a.x) | ((unsigned)f2bf(a.y) << 16);
  r.y = (unsigned)f2bf(a.z) | ((unsigned)f2bf(a.w) << 16);
  r.z = (unsigned)f2bf(b.x) | ((unsigned)f2bf(b.y) << 16);
  r.w = (unsigned)f2bf(b.z) | ((unsigned)f2bf(b.w) << 16);
  return r;
}

// ---------------- workspace layout (bytes) ----------------
#define OFF_R0 0ull
#define OFF_R1 44630016ull
#define OFF_R2 55787520ull
#define OFF_R3 66945024ull
#define OFF_WB 78102528ull
#define OFF_BI 79609856ull

// weight sub-offsets (bf16 elems)
#define WOF_V  0
#define WOF_OA 65536
#define WOF_P  163840
#define WOF_1  229376
#define WOF_2  491520
#define NWELEM 753664

#define OUT0 5570560ull   // 4*5440*256
#define OUT1 614400ull    // 4*75*8*256 (floats)

// ---------------------------------------------------------------------------
// Weight fp32 -> bf16 pack + fused [bo;ba] bias pack + all_vt passthrough
// copy (r10: folds the trailing hipMemcpyAsync into this kernel's tail
// blocks — removes one dispatch drain).
// ---------------------------------------------------------------------------
__global__ __launch_bounds__(256) void convw_k(
    const float* __restrict__ Wv, const float* __restrict__ Wo,
    const float* __restrict__ Wa, const float* __restrict__ Wp,
    const float* __restrict__ W1, const float* __restrict__ W2,
    const float* __restrict__ bo, const float* __restrict__ ba,
    u16* __restrict__ out, float* __restrict__ boa,
    const float* __restrict__ avt, float* __restrict__ avt_dst)
{
  const int b = blockIdx.x;
  if (b >= NWELEM / 256) {
    // all_vt copy: 614400 floats = 153600 float4 = 600 blocks x 256 lanes
    const int i = (b - NWELEM / 256) * 256 + threadIdx.x;
    ((float4*)avt_dst)[i] = ((const float4*)avt)[i];
    return;
  }
  const int gid = b * 256 + threadIdx.x;
  if (gid < 384) boa[gid] = (gid < 256) ? bo[gid] : ba[gid - 256];
  float v;
  if (gid < WOF_OA) {
    v = Wv[gid];
  } else if (gid < WOF_P) {
    const int o = gid - WOF_OA;
    v = (o < 65536) ? Wo[o] : Wa[o - 65536];
  } else if (gid < WOF_1) {
    v = Wp[gid - WOF_P];
  } else if (gid < WOF_2) {
    v = W1[gid - WOF_1];
  } else {
    v = W2[gid - WOF_2];
  }
  out[gid] = f2bf(v);
}

// ---------------------------------------------------------------------------
// FUSED HEAD GEMM (r9-proven): value = vin@Wv^T + bv AND [off|attn] =
// q@[Wo;Wa]^T + [bo;ba] in ONE dispatch. Unchanged this round.
// ---------------------------------------------------------------------------
__global__ __launch_bounds__(256) void headgemm_k(
    const float* __restrict__ src, const float* __restrict__ pos,
    const float* __restrict__ sel, const u16* __restrict__ WBp,
    const float* __restrict__ bv, const float* __restrict__ boa,
    u16* __restrict__ val_bf, float* __restrict__ oabuf)
{
  __shared__ u16 Av[32 * 256];        // 16 KB: vin chunk
  __shared__ u16 Aq[32 * 256];        // 16 KB: q chunk
  __shared__ u16 Bs[4 * 4096];        // 8 KB per wave: 2 x 4 KB dbuf strips
  const int tid = threadIdx.x;
  const int w = tid >> 6, lane = tid & 63;
  const int l15 = lane & 15, quad = lane >> 4;
  const int m0 = blockIdx.y * 32;
  const int swz = (quad ^ ((l15 >> 1) & 3)) * 8;

  const int rA = (tid & 127) >> 2;        // 0..31
  const int pA = tid & 3;
  const int jb = ((tid >> 7) & 1) * 4;    // tile group base: 0 or 4
  const int cA = (pA ^ ((rA >> 1) & 3)) * 8;
  const int ldsA = rA * 32 + pA * 8;
  int gmA = m0 + rA; if (gmA >= NR) gmA = NR - 1;
  const int an = gmA / LQ, ai = gmA - an * LQ;
  const float* aV; const float* aP = nullptr;
  if (ai < LSP) {
    aV = src + ((size_t)(an * LSP + ai)) * DM;
    aP = pos + ((size_t)(an * LSP + ai)) * DM;
  } else {
    aV = sel + ((size_t)(an * 8 + (ai - LSP))) * DM;   // q = vin = sel here
  }

#pragma unroll
  for (int i = 0; i < 4; i += 2) {
    const int j0 = jb + i, j1 = jb + i + 1;
    float4 v0a = *(const float4*)(aV + j0 * 32 + cA);
    float4 v0b = *(const float4*)(aV + j0 * 32 + cA + 4);
    float4 v1a = *(const float4*)(aV + j1 * 32 + cA);
    float4 v1b = *(const float4*)(aV + j1 * 32 + cA + 4);
    *(uint4v*)&Av[j0 * 1024 + ldsA] = pack8(v0a, v0b);
    *(uint4v*)&Av[j1 * 1024 + ldsA] = pack8(v1a, v1b);
    if (aP) {
      const float4 p0a = *(const float4*)(aP + j0 * 32 + cA);
      const float4 p0b = *(const float4*)(aP + j0 * 32 + cA + 4);
      const float4 p1a = *(const float4*)(aP + j1 * 32 + cA);
      const float4 p1b = *(const float4*)(aP + j1 * 32 + cA + 4);
      v0a.x += p0a.x; v0a.y += p0a.y; v0a.z += p0a.z; v0a.w += p0a.w;
      v0b.x += p0b.x; v0b.y += p0b.y; v0b.z += p0b.z; v0b.w += p0b.w;
      v1a.x += p1a.x; v1a.y += p1a.y; v1a.z += p1a.z; v1a.w += p1a.w;
      v1b.x += p1b.x; v1b.y += p1b.y; v1b.z += p1b.z; v1b.w += p1b.w;
    }
    *(uint4v*)&Aq[j0 * 1024 + ldsA] = pack8(v0a, v0b);
    *(uint4v*)&Aq[j1 * 1024 + ldsA] = pack8(v1a, v1b);
  }
  __syncthreads();

  int rB[4], cB[4], lB[4];
#pragma unroll
  for (int i = 0; i < 4; ++i) {
    const int g = lane + i * 64;
    rB[i] = g >> 2;
    const int p = g & 3;
    cB[i] = (p ^ ((rB[i] >> 1) & 3)) * 8;
    lB[i] = w * 4096 + rB[i] * 32 + p * 8;
  }

#pragma unroll
  for (int it = 0; it < 3; ++it) {
    const bool act = (it < 2) || (w < 2);
    const int coloff = (it == 2) ? 256 : 0;
    const u16* Brow = WBp + ((it == 0) ? WOF_V : WOF_OA)
                    + (size_t)(coloff + w * 64) * 256;
    const u16* Alds = (it == 0) ? Av : Aq;
    f32x4 acc[2][4] = {};

    if (act) {
      uint4v rb0[4], rb1[4];
#pragma unroll
      for (int i = 0; i < 4; ++i)
        rb0[i] = *(const uint4v*)(Brow + (size_t)rB[i] * 256 + cB[i]);
#pragma unroll
      for (int i = 0; i < 4; ++i)
        rb1[i] = *(const uint4v*)(Brow + (size_t)rB[i] * 256 + 32 + cB[i]);
#pragma unroll
      for (int i = 0; i < 4; ++i) *(uint4v*)&Bs[lB[i]] = rb0[i];

#pragma unroll
      for (int j = 0; j < 8; ++j) {
        if (j < 6) {
          if ((j & 1) == 0) {
#pragma unroll
            for (int i = 0; i < 4; ++i)
              rb0[i] = *(const uint4v*)(Brow + (size_t)rB[i] * 256 + (j + 2) * 32 + cB[i]);
          } else {
#pragma unroll
            for (int i = 0; i < 4; ++i)
              rb1[i] = *(const uint4v*)(Brow + (size_t)rB[i] * 256 + (j + 2) * 32 + cB[i]);
          }
        }
        short8 af[2], bfr[4];
#pragma unroll
        for (int r = 0; r < 2; ++r)
          af[r] = *(const short8*)&Alds[j * 1024 + (r * 16 + l15) * 32 + swz];
#pragma unroll
        for (int c = 0; c < 4; ++c)
          bfr[c] = *(const short8*)&Bs[w * 4096 + (j & 1) * 2048 + (c * 16 + l15) * 32 + swz];
        if (j < 7) {
          const int buf = ((j + 1) & 1) * 2048;
          if ((j & 1) == 0) {
#pragma unroll
            for (int i = 0; i < 4; ++i) *(uint4v*)&Bs[lB[i] + buf] = rb1[i];
          } else {
#pragma unroll
            for (int i = 0; i < 4; ++i) *(uint4v*)&Bs[lB[i] + buf] = rb0[i];
          }
        }
#pragma unroll
        for (int r = 0; r < 2; ++r)
#pragma unroll
          for (int c = 0; c < 4; ++c)
            acc[r][c] = __builtin_amdgcn_mfma_f32_16x16x32_bf16(af[r], bfr[c], acc[r][c], 0, 0, 0);
      }

      int col[4]; float bb[4];
#pragma unroll
      for (int c = 0; c < 4; ++c) {
        col[c] = coloff + w * 64 + c * 16 + l15;
        bb[c] = (it == 0) ? bv[col[c]] : boa[col[c]];
      }
      if (it == 0) {
#pragma unroll
        for (int c = 0; c < 4; ++c)
#pragma unroll
          for (int r = 0; r < 2; ++r)
#pragma unroll
            for (int j = 0; j < 4; ++j) {
              const int row = m0 + r * 16 + quad * 4 + j;
              if (row < NR)
                val_bf[(size_t)row * 256 + col[c]] = f2bf(acc[r][c][j] + bb[c]);
            }
      } else {
#pragma unroll
        for (int c = 0; c < 4; ++c)
#pragma unroll
          for (int r = 0; r < 2; ++r)
#pragma unroll
            for (int j = 0; j < 4; ++j) {
              const int row = m0 + r * 16 + quad * 4 + j;
              if (row < NR)
                oabuf[(size_t)row * 384 + col[c]] = acc[r][c][j] + bb[c];
            }
      }
    }
  }
}

// ---------------------------------------------------------------------------
// Pipelined MFMA GEMM — r7-exact dbuf j-loop, BM re-parameterized (r10).
// BM=32 for proj/ffn2 (proven). BM=64 for ffn1 ONLY: doubles B reuse per
// output row (A.I. 32->64 FLOP/B of B — the GEMMs are L2-BW-structural),
// grid (4,341)=1364 blocks stays well-fed at the 2-blocks/CU LDS cap.
// EPI: 0 bf16 out; 1 relu bf16 out; 2 LN1(residual src/sel) -> bf16 out;
//      3 LN2(residual xbf) -> fp32 scatter to d_out; 4 fp32 out (ldof).
// ---------------------------------------------------------------------------
template <int AMODE, int EPI, int BM, int BN, int NITER>
__global__ __launch_bounds__(BN) void gemmP(
    const u16* __restrict__ A, int lda,
    const float* __restrict__ src, const float* __restrict__ pos,
    const float* __restrict__ sel,
    const u16* __restrict__ B, int ldb,
    const float* __restrict__ bias, int K,
    u16* __restrict__ outb, int ldob,
    const u16* __restrict__ xbf,
    const float* __restrict__ gvec, const float* __restrict__ bvec,
    float* __restrict__ outf, int ldof)
{
  constexpr int NW = BN / 64;
  constexpr int MR = BM / 16;        // acc row-fragments per wave
  constexpr int TS = BM * 32;        // As u16 stride per 32-k tile
  constexpr int SL = BM * 4;         // (row,granule) staging slots per tile
  constexpr int NG = 256 / SL;       // staging thread-groups
  constexpr int TPG = 8 / NG;        // tiles per group
  __shared__ u16 As[BM * 256];       // full 256-K chunk of A
  __shared__ u16 Bs[NW * 4096];      // 8 KB per wave: 2 x 4 KB dbuf strips
  const int tid = threadIdx.x;
  const int w = tid >> 6, lane = tid & 63;
  const int l15 = lane & 15, quad = lane >> 4;
  const int m0 = blockIdx.y * BM;
  const int n0 = blockIdx.x * (BN * NITER);
  const int swz = (quad ^ ((l15 >> 1) & 3)) * 8;

  const int rA = (tid & (SL - 1)) >> 2;          // 0..BM-1
  const int pA = tid & 3;
  const int jb = ((tid / SL) & (NG - 1)) * TPG;  // tile group base
  const int cA = (pA ^ ((rA >> 1) & 3)) * 8;
  const int ldsA = rA * 32 + pA * 8;
  int gmA = m0 + rA; if (gmA >= NR) gmA = NR - 1;
  const float* aV = nullptr; const float* aP = nullptr;
  if (AMODE) {
    const int n = gmA / LQ, i = gmA - n * LQ;
    if (i < LSP) {
      aV = src + ((size_t)(n * LSP + i)) * DM;
      if (AMODE == 1) aP = pos + ((size_t)(n * LSP + i)) * DM;
    } else {
      aV = sel + ((size_t)(n * 8 + (i - LSP))) * DM;   // q = vin = sel here
    }
  }

  int rB[4], cB[4], lB[4];
#pragma unroll
  for (int i = 0; i < 4; ++i) {
    const int g = lane + i * 64;
    rB[i] = g >> 2;
    const int p = g & 3;
    cB[i] = (p ^ ((rB[i] >> 1) & 3)) * 8;
    lB[i] = w * 4096 + rB[i] * 32 + p * 8;
  }

  for (int it = 0; it < NITER; ++it) {
    const u16* Brow = B + (size_t)(n0 + it * BN + w * 64) * ldb;
    f32x4 acc[MR][4] = {};

    for (int kc = 0; kc < K; kc += 256) {
      if (NITER == 1 || it == 0) {
        if (kc) __syncthreads();
        if (tid < 256) {
          if (AMODE == 0) {
            const u16* ap = A + (size_t)gmA * lda + kc + cA;
#pragma unroll
            for (int t = 0; t < TPG; ++t) {
              const uint4v tt = *(const uint4v*)(ap + (jb + t) * 32);
              *(uint4v*)&As[(jb + t) * TS + ldsA] = tt;
            }
          } else {
#pragma unroll
            for (int i = 0; i < TPG; i += 2) {
              const int j0 = jb + i, j1 = jb + i + 1;
              float4 v0a = *(const float4*)(aV + kc + j0 * 32 + cA);
              float4 v0b = *(const float4*)(aV + kc + j0 * 32 + cA + 4);
              float4 v1a = *(const float4*)(aV + kc + j1 * 32 + cA);
              float4 v1b = *(const float4*)(aV + kc + j1 * 32 + cA + 4);
              if (AMODE == 1 && aP) {
                const float4 p0a = *(const float4*)(aP + kc + j0 * 32 + cA);
                const float4 p0b = *(const float4*)(aP + kc + j0 * 32 + cA + 4);
                const float4 p1a = *(const float4*)(aP + kc + j1 * 32 + cA);
                const float4 p1b = *(const float4*)(aP + kc + j1 * 32 + cA + 4);
                v0a.x += p0a.x; v0a.y += p0a.y; v0a.z += p0a.z; v0a.w += p0a.w;
                v0b.x += p0b.x; v0b.y += p0b.y; v0b.z += p0b.z; v0b.w += p0b.w;
                v1a.x += p1a.x; v1a.y += p1a.y; v1a.z += p1a.z; v1a.w += p1a.w;
                v1b.x += p1b.x; v1b.y += p1b.y; v1b.z += p1b.z; v1b.w += p1b.w;
              }
              *(uint4v*)&As[j0 * TS + ldsA] = pack8(v0a, v0b);
              *(uint4v*)&As[j1 * TS + ldsA] = pack8(v1a, v1b);
            }
          }
        }
        __syncthreads();
      }

      uint4v rb0[4], rb1[4];
#pragma unroll
      for (int i = 0; i < 4; ++i)
        rb0[i] = *(const uint4v*)(Brow + (size_t)rB[i] * ldb + kc + cB[i]);
#pragma unroll
      for (int i = 0; i < 4; ++i)
        rb1[i] = *(const uint4v*)(Brow + (size_t)rB[i] * ldb + kc + 32 + cB[i]);
#pragma unroll
      for (int i = 0; i < 4; ++i) *(uint4v*)&Bs[lB[i]] = rb0[i];

#pragma unroll
      for (int j = 0; j < 8; ++j) {
        if (j < 6) {
          if ((j & 1) == 0) {
#pragma unroll
            for (int i = 0; i < 4; ++i)
              rb0[i] = *(const uint4v*)(Brow + (size_t)rB[i] * ldb + kc + (j + 2) * 32 + cB[i]);
          } else {
#pragma unroll
            for (int i = 0; i < 4; ++i)
              rb1[i] = *(const uint4v*)(Brow + (size_t)rB[i] * ldb + kc + (j + 2) * 32 + cB[i]);
          }
        }
        short8 af[MR], bfr[4];
#pragma unroll
        for (int r = 0; r < MR; ++r)
          af[r] = *(const short8*)&As[j * TS + (r * 16 + l15) * 32 + swz];
#pragma unroll
        for (int c = 0; c < 4; ++c)
          bfr[c] = *(const short8*)&Bs[w * 4096 + (j & 1) * 2048 + (c * 16 + l15) * 32 + swz];
        if (j < 7) {
          const int buf = ((j + 1) & 1) * 2048;
          if ((j & 1) == 0) {
#pragma unroll
            for (int i = 0; i < 4; ++i) *(uint4v*)&Bs[lB[i] + buf] = rb1[i];
          } else {
#pragma unroll
            for (int i = 0; i < 4; ++i) *(uint4v*)&Bs[lB[i] + buf] = rb0[i];
          }
        }
#pragma unroll
        for (int r = 0; r < MR; ++r)
#pragma unroll
          for (int c = 0; c < 4; ++c)
            acc[r][c] = __builtin_amdgcn_mfma_f32_16x16x32_bf16(af[r], bfr[c], acc[r][c], 0, 0, 0);
      }
    }

    int col[4];
    float bb[4];
#pragma unroll
    for (int c = 0; c < 4; ++c) {
      col[c] = n0 + it * BN + w * 64 + c * 16 + l15;
      bb[c] = bias[col[c]];
    }

    if (EPI == 4) {
#pragma unroll
      for (int c = 0; c < 4; ++c)
#pragma unroll
        for (int r = 0; r < MR; ++r)
#pragma unroll
          for (int j = 0; j < 4; ++j) {
            const int row = m0 + r * 16 + quad * 4 + j;
            if (row < NR) outf[(size_t)row * ldof + col[c]] = acc[r][c][j] + bb[c];
          }
      continue;
    }

    if (EPI <= 1) {
#pragma unroll
      for (int c = 0; c < 4; ++c)
#pragma unroll
        for (int r = 0; r < MR; ++r)
#pragma unroll
          for (int j = 0; j < 4; ++j) {
            const int row = m0 + r * 16 + quad * 4 + j;
            if (row < NR) {
              float v = acc[r][c][j] + bb[c];
              if (EPI == 1) v = fmaxf(v, 0.f);
              outb[(size_t)row * ldob + col[c]] = f2bf(v);
            }
          }
      continue;
    }

    // ---- EPI 2/3: residual + LayerNorm fused epilogue (NITER==1 only) ----
    __syncthreads();   // all waves done reading As -> reuse as scratch
    float sv[MR][4], sq[MR][4];
#pragma unroll
    for (int r = 0; r < MR; ++r) {
#pragma unroll
      for (int j = 0; j < 4; ++j) {
        const int row = m0 + r * 16 + quad * 4 + j;
        const int rc = (row < NR) ? row : NR - 1;
        if (EPI == 2) {
          const int n = rc / LQ;
          const int i = rc - n * LQ;
          const float* resb = (i < LSP)
              ? src + ((size_t)(n * LSP + i)) * DM
              : sel + ((size_t)(n * 8 + (i - LSP))) * DM;
#pragma unroll
          for (int c = 0; c < 4; ++c) acc[r][c][j] += bb[c] + resb[col[c]];
        } else {
#pragma unroll
          for (int c = 0; c < 4; ++c)
            acc[r][c][j] += bb[c] + bf2f(xbf[(size_t)rc * DM + col[c]]);
        }
        float s = 0.f, q = 0.f;
#pragma unroll
        for (int c = 0; c < 4; ++c) {
          const float v = acc[r][c][j];
          s += v; q += v * v;
        }
        sv[r][j] = s; sq[r][j] = q;
      }
    }
#pragma unroll
    for (int off = 1; off < 16; off <<= 1) {
#pragma unroll
      for (int r = 0; r < MR; ++r)
#pragma unroll
        for (int j = 0; j < 4; ++j) {
          sv[r][j] += __shfl_xor(sv[r][j], off, 64);
          sq[r][j] += __shfl_xor(sq[r][j], off, 64);
        }
    }
    float* red = (float*)As;   // [BM rows][NW waves][2]
    if (l15 == 0) {
#pragma unroll
      for (int r = 0; r < MR; ++r)
#pragma unroll
        for (int j = 0; j < 4; ++j) {
          const int rl = r * 16 + quad * 4 + j;
          red[(rl * NW + w) * 2 + 0] = sv[r][j];
          red[(rl * NW + w) * 2 + 1] = sq[r][j];
        }
    }
    __syncthreads();

    float gg[4], b2[4];
#pragma unroll
    for (int c = 0; c < 4; ++c) { gg[c] = gvec[col[c]]; b2[c] = bvec[col[c]]; }

#pragma unroll
    for (int r = 0; r < MR; ++r) {
#pragma unroll
      for (int j = 0; j < 4; ++j) {
        const int row = m0 + r * 16 + quad * 4 + j;
        if (row >= NR) continue;
        const int rl = r * 16 + quad * 4 + j;
        float ms = 0.f, mq = 0.f;
#pragma unroll
        for (int ww = 0; ww < NW; ++ww) {
          ms += red[(rl * NW + ww) * 2 + 0];
          mq += red[(rl * NW + ww) * 2 + 1];
        }
        const float mean = ms * (1.f / 256.f);
        const float var = mq * (1.f / 256.f) - mean * mean;
        const float rin = rsqrtf(var + 1e-5f);
        if (EPI == 2) {
#pragma unroll
          for (int c = 0; c < 4; ++c)
            outb[(size_t)row * DM + col[c]] =
                f2bf(gg[c] * (acc[r][c][j] - mean) * rin + b2[c]);
        } else {
          const int n = row / LQ;
          const int i = row - n * LQ;
          float* dst = (i < LSP)
              ? outf + (size_t)(n * LSP + i) * DM
              : outf + OUT0 + OUT1 + (size_t)(n * 8 + (i - LSP)) * DM;
#pragma unroll
          for (int c = 0; c < 4; ++c)
            dst[col[c]] = gg[c] * (acc[r][c][j] - mean) * rin + b2[c];
        }
      }
    }
  }
}

// ---------------------------------------------------------------------------
// Deformable sampling v6 (r5/r7/r9-proven: ~52us, VALUBusy ~72%): branchless
// bilinear, LEVEL loop split across the two 32-lane wave halves, one
// shfl_xor(32) combine. XCD-affine block mapping; softmax fused.
// ---------------------------------------------------------------------------
__device__ __forceinline__ void fma8(float* a, const uint4v u, float w) {
  a[0] += w * __uint_as_float(u.x << 16);
  a[1] += w * __uint_as_float(u.x & 0xffff0000u);
  a[2] += w * __uint_as_float(u.y << 16);
  a[3] += w * __uint_as_float(u.y & 0xffff0000u);
  a[4] += w * __uint_as_float(u.z << 16);
  a[5] += w * __uint_as_float(u.z & 0xffff0000u);
  a[6] += w * __uint_as_float(u.w << 16);
  a[7] += w * __uint_as_float(u.w & 0xffff0000u);
}

__global__ __launch_bounds__(256) void sample4_k(
    const u16* __restrict__ value, const float* __restrict__ oa,
    const float* __restrict__ ref, u16* __restrict__ samp)
{
  const int lb = blockIdx.x;            // 0 .. 5447  (8 * 681)
  const int xcd = lb & 7;
  const int idx = lb >> 3;              // 0 .. 680
  const int batch = xcd >> 1;
  const int rg = idx * 2 + (xcd & 1);   // 0 .. 1361  (row-group of 4)
  const int lane = threadIdx.x & 63;
  const int hi = lane >> 5;             // level-half: 0 -> l=0,1 ; 1 -> l=2,3
  const int li = lane & 31;
  const int m = li >> 2, q4 = li & 3;
  const int row = batch * LQ + rg * 4 + (threadIdx.x >> 6);

  const float* oar = oa + (size_t)row * 384;
  const float* offm = oar + m * 32;

  const float4 lg = *(const float4*)(oar + 256 + m * 16 + q4 * 4);
  float mx = fmaxf(fmaxf(lg.x, lg.y), fmaxf(lg.z, lg.w));
  mx = fmaxf(mx, __shfl_xor(mx, 1, 64));
  mx = fmaxf(mx, __shfl_xor(mx, 2, 64));
  const float e0 = __expf(lg.x - mx), e1 = __expf(lg.y - mx),
              e2 = __expf(lg.z - mx), e3 = __expf(lg.w - mx);
  float s = e0 + e1 + e2 + e3;
  s += __shfl_xor(s, 1, 64);
  s += __shfl_xor(s, 2, 64);
  const float inv = 1.f / s;
  float wp[4] = {e0 * inv, e1 * inv, e2 * inv, e3 * inv};

  const int L0 = hi * 2;                // this half's first level
  float aw[2][4];
#pragma unroll
  for (int p = 0; p < 4; ++p) {
#pragma unroll
    for (int t = 0; t < 2; ++t)
      aw[t][p] = __shfl(wp[p], (lane & ~3) | (L0 + t), 64);
  }

  const float4 r01 = *(const float4*)(ref + (size_t)row * 8);
  const float4 r23 = *(const float4*)(ref + (size_t)row * 8 + 4);
  const float RXa[4] = {r01.x, r01.z, r23.x, r23.z};
  const float RYa[4] = {r01.y, r01.w, r23.y, r23.w};
  const int HW[4] = {64, 32, 16, 8};
  const int ST[4] = {0, 4096, 5120, 5376};

  float a[8] = {};
#pragma unroll
  for (int t = 0; t < 2; ++t) {
    const int l = L0 + t;
    const int W = HW[l];
    const float rx = RXa[l], ry = RYa[l];
    const u16* vb = value + ((size_t)(batch * LQ + ST[l])) * DM + m * 32 + q4 * 8;
    const float4 oA = *(const float4*)(offm + l * 8);
    const float4 oB = *(const float4*)(offm + l * 8 + 4);
    const float ox[4] = {oA.x, oA.z, oB.x, oB.z};
    const float oy[4] = {oA.y, oA.w, oB.y, oB.w};
#pragma unroll
    for (int p = 0; p < 4; ++p) {
      const float px = rx * (float)W + ox[p] - 0.5f;
      const float py = ry * (float)W + oy[p] - 0.5f;
      const float xf = floorf(px), yf = floorf(py);
      const float wx = px - xf, wy = py - yf;
      const int x0 = (int)xf, y0 = (int)yf;
      const int x1 = x0 + 1, y1 = y0 + 1;
      const float vx0 = ((x0 >= 0) & (x0 < W)) ? 1.f : 0.f;
      const float vx1 = ((x1 >= 0) & (x1 < W)) ? 1.f : 0.f;
      const float vy0 = ((y0 >= 0) & (y0 < W)) ? 1.f : 0.f;
      const float vy1 = ((y1 >= 0) & (y1 < W)) ? 1.f : 0.f;
      const int cx0 = min(max(x0, 0), W - 1), cx1 = min(max(x1, 0), W - 1);
      const int cy0 = min(max(y0, 0), W - 1), cy1 = min(max(y1, 0), W - 1);
      const float awp = aw[t][p];
      const float w00 = awp * (1.f - wx) * (1.f - wy) * vx0 * vy0;
      const float w01 = awp * wx * (1.f - wy) * vx1 * vy0;
      const float w10 = awp * (1.f - wx) * wy * vx0 * vy1;
      const float w11 = awp * wx * wy * vx1 * vy1;
      const uint4v v00 = *(const uint4v*)(vb + (size_t)(cy0 * W + cx0) * DM);
      const uint4v v01 = *(const uint4v*)(vb + (size_t)(cy0 * W + cx1) * DM);
      const uint4v v10 = *(const uint4v*)(vb + (size_t)(cy1 * W + cx0) * DM);
      const uint4v v11 = *(const uint4v*)(vb + (size_t)(cy1 * W + cx1) * DM);
      fma8(a, v00, w00);
      fma8(a, v01, w01);
      fma8(a, v10, w10);
      fma8(a, v11, w11);
    }
  }
#pragma unroll
  for (int i = 0; i < 8; ++i) a[i] += __shfl_xor(a[i], 32, 64);

  if (hi == 0) {
    uint4v ov;
    ov.x = (unsigned int)f2bf(a[0]) | ((unsigned int)f2bf(a[1]) << 16);
    ov.y = (unsigned int)f2bf(a[2]) | ((unsigned int)f2bf(a[3]) << 16);
    ov.z = (unsigned int)f2bf(a[4]) | ((unsigned int)f2bf(a[5]) << 16);
    ov.w = (unsigned int)f2bf(a[6]) | ((unsigned int)f2bf(a[7]) << 16);
    *(uint4v*)(samp + (size_t)row * DM + m * 32 + q4 * 8) = ov;
  }
}

// ---------------------------------------------------------------------------
extern "C" void kernel_launch(void* const* d_in, const int* in_sizes, int n_in,
                              void* d_out, int out_size, void* d_ws, size_t ws_size,
                              hipStream_t stream)
{
  const float* src = (const float*)d_in[0];
  const float* pos = (const float*)d_in[1];
  const float* ref = (const float*)d_in[2];
  const float* all_vt = (const float*)d_in[6];
  const float* sel = (const float*)d_in[7];
  const float* Wv = (const float*)d_in[8];
  const float* bv = (const float*)d_in[9];
  const float* Wo = (const float*)d_in[10];
  const float* bo = (const float*)d_in[11];
  const float* Wa = (const float*)d_in[12];
  const float* ba = (const float*)d_in[13];
  const float* Wp = (const float*)d_in[14];
  const float* bp = (const float*)d_in[15];
  const float* g1 = (const float*)d_in[16];
  const float* be1 = (const float*)d_in[17];
  const float* W1 = (const float*)d_in[18];
  const float* b1 = (const float*)d_in[19];
  const float* W2 = (const float*)d_in[20];
  const float* b2 = (const float*)d_in[21];
  const float* g2 = (const float*)d_in[22];
  const float* be2 = (const float*)d_in[23];

  char* ws = (char*)d_ws;
  float* oabuf = (float*)(ws + OFF_R0);   // dead after sample4
  u16* h_bf    = (u16*)(ws + OFF_R0);     // written by ffn1 (after oa dead)
  u16* samp_bf = (u16*)(ws + OFF_R1);
  u16* x_bf    = (u16*)(ws + OFF_R2);
  u16* val_bf  = (u16*)(ws + OFF_R3);
  u16* WB      = (u16*)(ws + OFF_WB);
  float* boa   = (float*)(ws + OFF_BI);

  const dim3 b256(256);
  const int MT32 = (NR + 31) / 32;    // 681 (exact: 21792 = 32*681)
  const int MT64 = (NR + 63) / 64;    // 341

  // weights pack + [bo;ba] pack + all_vt passthrough (600 tail blocks)
  convw_k<<<dim3(NWELEM / 256 + 600), b256, 0, stream>>>(
      Wv, Wo, Wa, Wp, W1, W2, bo, ba, WB, boa,
      all_vt, (float*)d_out + OUT0);
  // FUSED: value = vin@Wv^T + bv  AND  [off|attn] = q@[Wo;Wa]^T + [bo;ba]
  headgemm_k<<<dim3(1, MT32), b256, 0, stream>>>(
      src, pos, sel, WB, bv, boa, val_bf, oabuf);
  // sampling (softmax fused), level-split across wave halves
  sample4_k<<<dim3(8 * 681), b256, 0, stream>>>(val_bf, oabuf, ref, samp_bf);
  // x = LN(v_in + samp @ Wp^T + bp) -> x_bf   (LN1 fused epilogue)
  gemmP<0, 2, 32, 256, 1><<<dim3(1, MT32), b256, 0, stream>>>(
      samp_bf, 256, src, nullptr, sel, WB + WOF_P, 256, bp, 256,
      x_bf, 256, nullptr, g1, be1, nullptr, 0);
  // h = relu(x @ W1^T + b1)  N=1024: BM=64, grid (4,341) — B-reuse doubled
  gemmP<0, 1, 64, 256, 1><<<dim3(4, MT64), b256, 0, stream>>>(
      x_bf, 256, nullptr, nullptr, nullptr, WB + WOF_1, 256, b1, 256,
      h_bf, 1024, nullptr, nullptr, nullptr, nullptr, 0);
  // out = LN(x + h @ W2^T + b2) scattered to d_out  (LN2 fused epilogue)
  gemmP<0, 3, 32, 256, 1><<<dim3(1, MT32), b256, 0, stream>>>(
      h_bf, 1024, nullptr, nullptr, nullptr, WB + WOF_2, 1024, b2, 1024,
      nullptr, 0, x_bf, g2, be2, (float*)d_out, 0);
}

// Round 12
// 274.119 us; speedup vs baseline: 1.0393x; 1.0393x over previous
//
#include <hip/hip_runtime.h>
#include <math.h>

#define NB   4
#define LQ   5448
#define LSP  5440
#define NR   21792   // NB * LQ
#define DM   256

typedef unsigned short u16;
typedef __attribute__((ext_vector_type(8))) short short8;   // 8 bf16 (4 VGPR)
typedef __attribute__((ext_vector_type(4))) float f32x4;    // MFMA acc
typedef __attribute__((ext_vector_type(4))) unsigned int uint4v; // 16B move

__device__ __forceinline__ u16 f2bf(float f) {
  unsigned int u = __float_as_uint(f);
  u = (u + 0x7fff + ((u >> 16) & 1)) >> 16;   // RNE
  return (u16)u;
}
__device__ __forceinline__ float bf2f(u16 u) {
  return __uint_as_float(((unsigned int)u) << 16);
}
__device__ __forceinline__ uint4v pack8(float4 a, float4 b) {
  uint4v r;
  r.x = (unsigned)f2bf(a.x) | ((unsigned)f2bf(a.y) << 16);
  r.y = (unsigned)f2bf(a.z) | ((unsigned)f2bf(a.w) << 16);
  r.z = (unsigned)f2bf(b.x) | ((unsigned)f2bf(b.y) << 16);
  r.w = (unsigned)f2bf(b.z) | ((unsigned)f2bf(b.w) << 16);
  return r;
}

// ---------------- workspace layout (bytes) ----------------
#define OFF_R0 0ull
#define OFF_R1 44630016ull
#define OFF_R2 55787520ull
#define OFF_R3 66945024ull
#define OFF_WB 78102528ull
#define OFF_BI 79609856ull

// weight sub-offsets (bf16 elems)
#define WOF_V  0
#define WOF_OA 65536
#define WOF_P  163840
#define WOF_1  229376
#define WOF_2  491520
#define NWELEM 753664

#define OUT0 5570560ull   // 4*5440*256
#define OUT1 614400ull    // 4*75*8*256 (floats)

// ---------------------------------------------------------------------------
// Weight fp32 -> bf16 pack + fused [bo;ba] bias pack + all_vt passthrough
// copy (r10 fold, kept: removes the trailing memcpy dispatch).
// ---------------------------------------------------------------------------
__global__ __launch_bounds__(256) void convw_k(
    const float* __restrict__ Wv, const float* __restrict__ Wo,
    const float* __restrict__ Wa, const float* __restrict__ Wp,
    const float* __restrict__ W1, const float* __restrict__ W2,
    const float* __restrict__ bo, const float* __restrict__ ba,
    u16* __restrict__ out, float* __restrict__ boa,
    const float* __restrict__ avt, float* __restrict__ avt_dst)
{
  const int b = blockIdx.x;
  if (b >= NWELEM / 256) {
    // all_vt copy: 614400 floats = 153600 float4 = 600 blocks x 256 lanes
    const int i = (b - NWELEM / 256) * 256 + threadIdx.x;
    ((float4*)avt_dst)[i] = ((const float4*)avt)[i];
    return;
  }
  const int gid = b * 256 + threadIdx.x;
  if (gid < 384) boa[gid] = (gid < 256) ? bo[gid] : ba[gid - 256];
  float v;
  if (gid < WOF_OA) {
    v = Wv[gid];
  } else if (gid < WOF_P) {
    const int o = gid - WOF_OA;
    v = (o < 65536) ? Wo[o] : Wa[o - 65536];
  } else if (gid < WOF_1) {
    v = Wp[gid - WOF_P];
  } else if (gid < WOF_2) {
    v = W1[gid - WOF_1];
  } else {
    v = W2[gid - WOF_2];
  }
  out[gid] = f2bf(v);
}

// ---------------------------------------------------------------------------
// FUSED HEAD GEMM (r9-proven): value = vin@Wv^T + bv AND [off|attn] =
// q@[Wo;Wa]^T + [bo;ba] in ONE dispatch. Unchanged.
// ---------------------------------------------------------------------------
__global__ __launch_bounds__(256) void headgemm_k(
    const float* __restrict__ src, const float* __restrict__ pos,
    const float* __restrict__ sel, const u16* __restrict__ WBp,
    const float* __restrict__ bv, const float* __restrict__ boa,
    u16* __restrict__ val_bf, float* __restrict__ oabuf)
{
  __shared__ u16 Av[32 * 256];        // 16 KB: vin chunk
  __shared__ u16 Aq[32 * 256];        // 16 KB: q chunk
  __shared__ u16 Bs[4 * 4096];        // 8 KB per wave: 2 x 4 KB dbuf strips
  const int tid = threadIdx.x;
  const int w = tid >> 6, lane = tid & 63;
  const int l15 = lane & 15, quad = lane >> 4;
  const int m0 = blockIdx.y * 32;
  const int swz = (quad ^ ((l15 >> 1) & 3)) * 8;

  const int rA = (tid & 127) >> 2;        // 0..31
  const int pA = tid & 3;
  const int jb = ((tid >> 7) & 1) * 4;    // tile group base: 0 or 4
  const int cA = (pA ^ ((rA >> 1) & 3)) * 8;
  const int ldsA = rA * 32 + pA * 8;
  int gmA = m0 + rA; if (gmA >= NR) gmA = NR - 1;
  const int an = gmA / LQ, ai = gmA - an * LQ;
  const float* aV; const float* aP = nullptr;
  if (ai < LSP) {
    aV = src + ((size_t)(an * LSP + ai)) * DM;
    aP = pos + ((size_t)(an * LSP + ai)) * DM;
  } else {
    aV = sel + ((size_t)(an * 8 + (ai - LSP))) * DM;   // q = vin = sel here
  }

#pragma unroll
  for (int i = 0; i < 4; i += 2) {
    const int j0 = jb + i, j1 = jb + i + 1;
    float4 v0a = *(const float4*)(aV + j0 * 32 + cA);
    float4 v0b = *(const float4*)(aV + j0 * 32 + cA + 4);
    float4 v1a = *(const float4*)(aV + j1 * 32 + cA);
    float4 v1b = *(const float4*)(aV + j1 * 32 + cA + 4);
    *(uint4v*)&Av[j0 * 1024 + ldsA] = pack8(v0a, v0b);
    *(uint4v*)&Av[j1 * 1024 + ldsA] = pack8(v1a, v1b);
    if (aP) {
      const float4 p0a = *(const float4*)(aP + j0 * 32 + cA);
      const float4 p0b = *(const float4*)(aP + j0 * 32 + cA + 4);
      const float4 p1a = *(const float4*)(aP + j1 * 32 + cA);
      const float4 p1b = *(const float4*)(aP + j1 * 32 + cA + 4);
      v0a.x += p0a.x; v0a.y += p0a.y; v0a.z += p0a.z; v0a.w += p0a.w;
      v0b.x += p0b.x; v0b.y += p0b.y; v0b.z += p0b.z; v0b.w += p0b.w;
      v1a.x += p1a.x; v1a.y += p1a.y; v1a.z += p1a.z; v1a.w += p1a.w;
      v1b.x += p1b.x; v1b.y += p1b.y; v1b.z += p1b.z; v1b.w += p1b.w;
    }
    *(uint4v*)&Aq[j0 * 1024 + ldsA] = pack8(v0a, v0b);
    *(uint4v*)&Aq[j1 * 1024 + ldsA] = pack8(v1a, v1b);
  }
  __syncthreads();

  int rB[4], cB[4], lB[4];
#pragma unroll
  for (int i = 0; i < 4; ++i) {
    const int g = lane + i * 64;
    rB[i] = g >> 2;
    const int p = g & 3;
    cB[i] = (p ^ ((rB[i] >> 1) & 3)) * 8;
    lB[i] = w * 4096 + rB[i] * 32 + p * 8;
  }

#pragma unroll
  for (int it = 0; it < 3; ++it) {
    const bool act = (it < 2) || (w < 2);
    const int coloff = (it == 2) ? 256 : 0;
    const u16* Brow = WBp + ((it == 0) ? WOF_V : WOF_OA)
                    + (size_t)(coloff + w * 64) * 256;
    const u16* Alds = (it == 0) ? Av : Aq;
    f32x4 acc[2][4] = {};

    if (act) {
      uint4v rb0[4], rb1[4];
#pragma unroll
      for (int i = 0; i < 4; ++i)
        rb0[i] = *(const uint4v*)(Brow + (size_t)rB[i] * 256 + cB[i]);
#pragma unroll
      for (int i = 0; i < 4; ++i)
        rb1[i] = *(const uint4v*)(Brow + (size_t)rB[i] * 256 + 32 + cB[i]);
#pragma unroll
      for (int i = 0; i < 4; ++i) *(uint4v*)&Bs[lB[i]] = rb0[i];

#pragma unroll
      for (int j = 0; j < 8; ++j) {
        if (j < 6) {
          if ((j & 1) == 0) {
#pragma unroll
            for (int i = 0; i < 4; ++i)
              rb0[i] = *(const uint4v*)(Brow + (size_t)rB[i] * 256 + (j + 2) * 32 + cB[i]);
          } else {
#pragma unroll
            for (int i = 0; i < 4; ++i)
              rb1[i] = *(const uint4v*)(Brow + (size_t)rB[i] * 256 + (j + 2) * 32 + cB[i]);
          }
        }
        short8 af[2], bfr[4];
#pragma unroll
        for (int r = 0; r < 2; ++r)
          af[r] = *(const short8*)&Alds[j * 1024 + (r * 16 + l15) * 32 + swz];
#pragma unroll
        for (int c = 0; c < 4; ++c)
          bfr[c] = *(const short8*)&Bs[w * 4096 + (j & 1) * 2048 + (c * 16 + l15) * 32 + swz];
        if (j < 7) {
          const int buf = ((j + 1) & 1) * 2048;
          if ((j & 1) == 0) {
#pragma unroll
            for (int i = 0; i < 4; ++i) *(uint4v*)&Bs[lB[i] + buf] = rb1[i];
          } else {
#pragma unroll
            for (int i = 0; i < 4; ++i) *(uint4v*)&Bs[lB[i] + buf] = rb0[i];
          }
        }
#pragma unroll
        for (int r = 0; r < 2; ++r)
#pragma unroll
          for (int c = 0; c < 4; ++c)
            acc[r][c] = __builtin_amdgcn_mfma_f32_16x16x32_bf16(af[r], bfr[c], acc[r][c], 0, 0, 0);
      }

      int col[4]; float bb[4];
#pragma unroll
      for (int c = 0; c < 4; ++c) {
        col[c] = coloff + w * 64 + c * 16 + l15;
        bb[c] = (it == 0) ? bv[col[c]] : boa[col[c]];
      }
      if (it == 0) {
#pragma unroll
        for (int c = 0; c < 4; ++c)
#pragma unroll
          for (int r = 0; r < 2; ++r)
#pragma unroll
            for (int j = 0; j < 4; ++j) {
              const int row = m0 + r * 16 + quad * 4 + j;
              if (row < NR)
                val_bf[(size_t)row * 256 + col[c]] = f2bf(acc[r][c][j] + bb[c]);
            }
      } else {
#pragma unroll
        for (int c = 0; c < 4; ++c)
#pragma unroll
          for (int r = 0; r < 2; ++r)
#pragma unroll
            for (int j = 0; j < 4; ++j) {
              const int row = m0 + r * 16 + quad * 4 + j;
              if (row < NR)
                oabuf[(size_t)row * 384 + col[c]] = acc[r][c][j] + bb[c];
            }
      }
    }
  }
}

// ---------------------------------------------------------------------------
// Pipelined MFMA GEMM, BM=32 (the empirical fixed point: BM=16 and BM=64
// both regressed), BN = 64*NW. r3/r7-exact dbuf j-loop. Used for proj
// (EPI2), ffn1 (EPI1, NITER=4 — r9-proven), ffn2 (EPI3).
// ---------------------------------------------------------------------------
template <int AMODE, int EPI, int BN, int NITER>
__global__ __launch_bounds__(BN) void gemmP(
    const u16* __restrict__ A, int lda,
    const float* __restrict__ src, const float* __restrict__ pos,
    const float* __restrict__ sel,
    const u16* __restrict__ B, int ldb,
    const float* __restrict__ bias, int K,
    u16* __restrict__ outb, int ldob,
    const u16* __restrict__ xbf,
    const float* __restrict__ gvec, const float* __restrict__ bvec,
    float* __restrict__ outf, int ldof)
{
  constexpr int NW = BN / 64;
  __shared__ u16 As[32 * 256];        // 16 KB: full 256-K chunk of A (32 rows)
  __shared__ u16 Bs[NW * 4096];       // 8 KB per wave: 2 x 4 KB dbuf strips
  const int tid = threadIdx.x;
  const int w = tid >> 6, lane = tid & 63;
  const int l15 = lane & 15, quad = lane >> 4;
  const int m0 = blockIdx.y * 32;
  const int n0 = blockIdx.x * (BN * NITER);
  const int swz = (quad ^ ((l15 >> 1) & 3)) * 8;

  const int rA = (tid & 127) >> 2;        // 0..31
  const int pA = tid & 3;
  const int jb = ((tid >> 7) & 1) * 4;    // tile group base: 0 or 4
  const int cA = (pA ^ ((rA >> 1) & 3)) * 8;
  const int ldsA = rA * 32 + pA * 8;
  int gmA = m0 + rA; if (gmA >= NR) gmA = NR - 1;
  const float* aV = nullptr; const float* aP = nullptr;
  if (AMODE) {
    const int n = gmA / LQ, i = gmA - n * LQ;
    if (i < LSP) {
      aV = src + ((size_t)(n * LSP + i)) * DM;
      if (AMODE == 1) aP = pos + ((size_t)(n * LSP + i)) * DM;
    } else {
      aV = sel + ((size_t)(n * 8 + (i - LSP))) * DM;   // q = vin = sel here
    }
  }

  int rB[4], cB[4], lB[4];
#pragma unroll
  for (int i = 0; i < 4; ++i) {
    const int g = lane + i * 64;
    rB[i] = g >> 2;
    const int p = g & 3;
    cB[i] = (p ^ ((rB[i] >> 1) & 3)) * 8;
    lB[i] = w * 4096 + rB[i] * 32 + p * 8;
  }

  for (int it = 0; it < NITER; ++it) {
    const u16* Brow = B + (size_t)(n0 + it * BN + w * 64) * ldb;
    f32x4 acc[2][4] = {};

    for (int kc = 0; kc < K; kc += 256) {
      if (NITER == 1 || it == 0) {
        if (kc) __syncthreads();
        if (tid < 256) {
          if (AMODE == 0) {
            const u16* ap = A + (size_t)gmA * lda + kc + cA;
            uint4v t0 = *(const uint4v*)(ap + (jb + 0) * 32);
            uint4v t1 = *(const uint4v*)(ap + (jb + 1) * 32);
            uint4v t2 = *(const uint4v*)(ap + (jb + 2) * 32);
            uint4v t3 = *(const uint4v*)(ap + (jb + 3) * 32);
            *(uint4v*)&As[(jb + 0) * 1024 + ldsA] = t0;
            *(uint4v*)&As[(jb + 1) * 1024 + ldsA] = t1;
            *(uint4v*)&As[(jb + 2) * 1024 + ldsA] = t2;
            *(uint4v*)&As[(jb + 3) * 1024 + ldsA] = t3;
          } else {
#pragma unroll
            for (int i = 0; i < 4; i += 2) {
              const int j0 = jb + i, j1 = jb + i + 1;
              float4 v0a = *(const float4*)(aV + kc + j0 * 32 + cA);
              float4 v0b = *(const float4*)(aV + kc + j0 * 32 + cA + 4);
              float4 v1a = *(const float4*)(aV + kc + j1 * 32 + cA);
              float4 v1b = *(const float4*)(aV + kc + j1 * 32 + cA + 4);
              if (AMODE == 1 && aP) {
                const float4 p0a = *(const float4*)(aP + kc + j0 * 32 + cA);
                const float4 p0b = *(const float4*)(aP + kc + j0 * 32 + cA + 4);
                const float4 p1a = *(const float4*)(aP + kc + j1 * 32 + cA);
                const float4 p1b = *(const float4*)(aP + kc + j1 * 32 + cA + 4);
                v0a.x += p0a.x; v0a.y += p0a.y; v0a.z += p0a.z; v0a.w += p0a.w;
                v0b.x += p0b.x; v0b.y += p0b.y; v0b.z += p0b.z; v0b.w += p0b.w;
                v1a.x += p1a.x; v1a.y += p1a.y; v1a.z += p1a.z; v1a.w += p1a.w;
                v1b.x += p1b.x; v1b.y += p1b.y; v1b.z += p1b.z; v1b.w += p1b.w;
              }
              *(uint4v*)&As[j0 * 1024 + ldsA] = pack8(v0a, v0b);
              *(uint4v*)&As[j1 * 1024 + ldsA] = pack8(v1a, v1b);
            }
          }
        }
        __syncthreads();
      }

      uint4v rb0[4], rb1[4];
#pragma unroll
      for (int i = 0; i < 4; ++i)
        rb0[i] = *(const uint4v*)(Brow + (size_t)rB[i] * ldb + kc + cB[i]);
#pragma unroll
      for (int i = 0; i < 4; ++i)
        rb1[i] = *(const uint4v*)(Brow + (size_t)rB[i] * ldb + kc + 32 + cB[i]);
#pragma unroll
      for (int i = 0; i < 4; ++i) *(uint4v*)&Bs[lB[i]] = rb0[i];

#pragma unroll
      for (int j = 0; j < 8; ++j) {
        if (j < 6) {
          if ((j & 1) == 0) {
#pragma unroll
            for (int i = 0; i < 4; ++i)
              rb0[i] = *(const uint4v*)(Brow + (size_t)rB[i] * ldb + kc + (j + 2) * 32 + cB[i]);
          } else {
#pragma unroll
            for (int i = 0; i < 4; ++i)
              rb1[i] = *(const uint4v*)(Brow + (size_t)rB[i] * ldb + kc + (j + 2) * 32 + cB[i]);
          }
        }
        short8 af[2], bfr[4];
#pragma unroll
        for (int r = 0; r < 2; ++r)
          af[r] = *(const short8*)&As[j * 1024 + (r * 16 + l15) * 32 + swz];
#pragma unroll
        for (int c = 0; c < 4; ++c)
          bfr[c] = *(const short8*)&Bs[w * 4096 + (j & 1) * 2048 + (c * 16 + l15) * 32 + swz];
        if (j < 7) {
          const int buf = ((j + 1) & 1) * 2048;
          if ((j & 1) == 0) {
#pragma unroll
            for (int i = 0; i < 4; ++i) *(uint4v*)&Bs[lB[i] + buf] = rb1[i];
          } else {
#pragma unroll
            for (int i = 0; i < 4; ++i) *(uint4v*)&Bs[lB[i] + buf] = rb0[i];
          }
        }
#pragma unroll
        for (int r = 0; r < 2; ++r)
#pragma unroll
          for (int c = 0; c < 4; ++c)
            acc[r][c] = __builtin_amdgcn_mfma_f32_16x16x32_bf16(af[r], bfr[c], acc[r][c], 0, 0, 0);
      }
    }

    int col[4];
    float bb[4];
#pragma unroll
    for (int c = 0; c < 4; ++c) {
      col[c] = n0 + it * BN + w * 64 + c * 16 + l15;
      bb[c] = bias[col[c]];
    }

    if (EPI == 4) {
#pragma unroll
      for (int c = 0; c < 4; ++c)
#pragma unroll
        for (int r = 0; r < 2; ++r)
#pragma unroll
          for (int j = 0; j < 4; ++j) {
            const int row = m0 + r * 16 + quad * 4 + j;
            if (row < NR) outf[(size_t)row * ldof + col[c]] = acc[r][c][j] + bb[c];
          }
      continue;
    }

    if (EPI <= 1) {
#pragma unroll
      for (int c = 0; c < 4; ++c)
#pragma unroll
        for (int r = 0; r < 2; ++r)
#pragma unroll
          for (int j = 0; j < 4; ++j) {
            const int row = m0 + r * 16 + quad * 4 + j;
            if (row < NR) {
              float v = acc[r][c][j] + bb[c];
              if (EPI == 1) v = fmaxf(v, 0.f);
              outb[(size_t)row * ldob + col[c]] = f2bf(v);
            }
          }
      continue;
    }

    // ---- EPI 2/3: residual + LayerNorm fused epilogue (NITER==1 only) ----
    __syncthreads();   // all waves done reading As -> reuse as scratch
    float sv[2][4], sq[2][4];
#pragma unroll
    for (int r = 0; r < 2; ++r) {
#pragma unroll
      for (int j = 0; j < 4; ++j) {
        const int row = m0 + r * 16 + quad * 4 + j;
        const int rc = (row < NR) ? row : NR - 1;
        if (EPI == 2) {
          const int n = rc / LQ;
          const int i = rc - n * LQ;
          const float* resb = (i < LSP)
              ? src + ((size_t)(n * LSP + i)) * DM
              : sel + ((size_t)(n * 8 + (i - LSP))) * DM;
#pragma unroll
          for (int c = 0; c < 4; ++c) acc[r][c][j] += bb[c] + resb[col[c]];
        } else {
#pragma unroll
          for (int c = 0; c < 4; ++c)
            acc[r][c][j] += bb[c] + bf2f(xbf[(size_t)rc * DM + col[c]]);
        }
        float s = 0.f, q = 0.f;
#pragma unroll
        for (int c = 0; c < 4; ++c) {
          const float v = acc[r][c][j];
          s += v; q += v * v;
        }
        sv[r][j] = s; sq[r][j] = q;
      }
    }
#pragma unroll
    for (int off = 1; off < 16; off <<= 1) {
#pragma unroll
      for (int r = 0; r < 2; ++r)
#pragma unroll
        for (int j = 0; j < 4; ++j) {
          sv[r][j] += __shfl_xor(sv[r][j], off, 64);
          sq[r][j] += __shfl_xor(sq[r][j], off, 64);
        }
    }
    float* red = (float*)As;   // [32 rows][4 waves][2]
    if (l15 == 0) {
#pragma unroll
      for (int r = 0; r < 2; ++r)
#pragma unroll
        for (int j = 0; j < 4; ++j) {
          const int rl = r * 16 + quad * 4 + j;
          red[(rl * 4 + w) * 2 + 0] = sv[r][j];
          red[(rl * 4 + w) * 2 + 1] = sq[r][j];
        }
    }
    __syncthreads();

    float gg[4], b2[4];
#pragma unroll
    for (int c = 0; c < 4; ++c) { gg[c] = gvec[col[c]]; b2[c] = bvec[col[c]]; }

#pragma unroll
    for (int r = 0; r < 2; ++r) {
#pragma unroll
      for (int j = 0; j < 4; ++j) {
        const int row = m0 + r * 16 + quad * 4 + j;
        if (row >= NR) continue;
        const int rl = r * 16 + quad * 4 + j;
        float ms = 0.f, mq = 0.f;
#pragma unroll
        for (int ww = 0; ww < 4; ++ww) {
          ms += red[(rl * 4 + ww) * 2 + 0];
          mq += red[(rl * 4 + ww) * 2 + 1];
        }
        const float mean = ms * (1.f / 256.f);
        const float var = mq * (1.f / 256.f) - mean * mean;
        const float rin = rsqrtf(var + 1e-5f);
        if (EPI == 2) {
#pragma unroll
          for (int c = 0; c < 4; ++c)
            outb[(size_t)row * DM + col[c]] =
                f2bf(gg[c] * (acc[r][c][j] - mean) * rin + b2[c]);
        } else {
          const int n = row / LQ;
          const int i = row - n * LQ;
          float* dst = (i < LSP)
              ? outf + (size_t)(n * LSP + i) * DM
              : outf + OUT0 + OUT1 + (size_t)(n * 8 + (i - LSP)) * DM;
#pragma unroll
          for (int c = 0; c < 4; ++c)
            dst[col[c]] = gg[c] * (acc[r][c][j] - mean) * rin + b2[c];
        }
      }
    }
  }
}

// ---------------------------------------------------------------------------
// Deformable sampling v6 (r5/r7/r9-proven: ~52us, VALUBusy ~72%): branchless
// bilinear, LEVEL loop split across the two 32-lane wave halves, one
// shfl_xor(32) combine. XCD-affine block mapping; softmax fused.
// ---------------------------------------------------------------------------
__device__ __forceinline__ void fma8(float* a, const uint4v u, float w) {
  a[0] += w * __uint_as_float(u.x << 16);
  a[1] += w * __uint_as_float(u.x & 0xffff0000u);
  a[2] += w * __uint_as_float(u.y << 16);
  a[3] += w * __uint_as_float(u.y & 0xffff0000u);
  a[4] += w * __uint_as_float(u.z << 16);
  a[5] += w * __uint_as_float(u.z & 0xffff0000u);
  a[6] += w * __uint_as_float(u.w << 16);
  a[7] += w * __uint_as_float(u.w & 0xffff0000u);
}

__global__ __launch_bounds__(256) void sample4_k(
    const u16* __restrict__ value, const float* __restrict__ oa,
    const float* __restrict__ ref, u16* __restrict__ samp)
{
  const int lb = blockIdx.x;            // 0 .. 5447  (8 * 681)
  const int xcd = lb & 7;
  const int idx = lb >> 3;              // 0 .. 680
  const int batch = xcd >> 1;
  const int rg = idx * 2 + (xcd & 1);   // 0 .. 1361  (row-group of 4)
  const int lane = threadIdx.x & 63;
  const int hi = lane >> 5;             // level-half: 0 -> l=0,1 ; 1 -> l=2,3
  const int li = lane & 31;
  const int m = li >> 2, q4 = li & 3;
  const int row = batch * LQ + rg * 4 + (threadIdx.x >> 6);

  const float* oar = oa + (size_t)row * 384;
  const float* offm = oar + m * 32;

  const float4 lg = *(const float4*)(oar + 256 + m * 16 + q4 * 4);
  float mx = fmaxf(fmaxf(lg.x, lg.y), fmaxf(lg.z, lg.w));
  mx = fmaxf(mx, __shfl_xor(mx, 1, 64));
  mx = fmaxf(mx, __shfl_xor(mx, 2, 64));
  const float e0 = __expf(lg.x - mx), e1 = __expf(lg.y - mx),
              e2 = __expf(lg.z - mx), e3 = __expf(lg.w - mx);
  float s = e0 + e1 + e2 + e3;
  s += __shfl_xor(s, 1, 64);
  s += __shfl_xor(s, 2, 64);
  const float inv = 1.f / s;
  float wp[4] = {e0 * inv, e1 * inv, e2 * inv, e3 * inv};

  const int L0 = hi * 2;                // this half's first level
  float aw[2][4];
#pragma unroll
  for (int p = 0; p < 4; ++p) {
#pragma unroll
    for (int t = 0; t < 2; ++t)
      aw[t][p] = __shfl(wp[p], (lane & ~3) | (L0 + t), 64);
  }

  const float4 r01 = *(const float4*)(ref + (size_t)row * 8);
  const float4 r23 = *(const float4*)(ref + (size_t)row * 8 + 4);
  const float RXa[4] = {r01.x, r01.z, r23.x, r23.z};
  const float RYa[4] = {r01.y, r01.w, r23.y, r23.w};
  const int HW[4] = {64, 32, 16, 8};
  const int ST[4] = {0, 4096, 5120, 5376};

  float a[8] = {};
#pragma unroll
  for (int t = 0; t < 2; ++t) {
    const int l = L0 + t;
    const int W = HW[l];
    const float rx = RXa[l], ry = RYa[l];
    const u16* vb = value + ((size_t)(batch * LQ + ST[l])) * DM + m * 32 + q4 * 8;
    const float4 oA = *(const float4*)(offm + l * 8);
    const float4 oB = *(const float4*)(offm + l * 8 + 4);
    const float ox[4] = {oA.x, oA.z, oB.x, oB.z};
    const float oy[4] = {oA.y, oA.w, oB.y, oB.w};
#pragma unroll
    for (int p = 0; p < 4; ++p) {
      const float px = rx * (float)W + ox[p] - 0.5f;
      const float py = ry * (float)W + oy[p] - 0.5f;
      const float xf = floorf(px), yf = floorf(py);
      const float wx = px - xf, wy = py - yf;
      const int x0 = (int)xf, y0 = (int)yf;
      const int x1 = x0 + 1, y1 = y0 + 1;
      const float vx0 = ((x0 >= 0) & (x0 < W)) ? 1.f : 0.f;
      const float vx1 = ((x1 >= 0) & (x1 < W)) ? 1.f : 0.f;
      const float vy0 = ((y0 >= 0) & (y0 < W)) ? 1.f : 0.f;
      const float vy1 = ((y1 >= 0) & (y1 < W)) ? 1.f : 0.f;
      const int cx0 = min(max(x0, 0), W - 1), cx1 = min(max(x1, 0), W - 1);
      const int cy0 = min(max(y0, 0), W - 1), cy1 = min(max(y1, 0), W - 1);
      const float awp = aw[t][p];
      const float w00 = awp * (1.f - wx) * (1.f - wy) * vx0 * vy0;
      const float w01 = awp * wx * (1.f - wy) * vx1 * vy0;
      const float w10 = awp * (1.f - wx) * wy * vx0 * vy1;
      const float w11 = awp * wx * wy * vx1 * vy1;
      const uint4v v00 = *(const uint4v*)(vb + (size_t)(cy0 * W + cx0) * DM);
      const uint4v v01 = *(const uint4v*)(vb + (size_t)(cy0 * W + cx1) * DM);
      const uint4v v10 = *(const uint4v*)(vb + (size_t)(cy1 * W + cx0) * DM);
      const uint4v v11 = *(const uint4v*)(vb + (size_t)(cy1 * W + cx1) * DM);
      fma8(a, v00, w00);
      fma8(a, v01, w01);
      fma8(a, v10, w10);
      fma8(a, v11, w11);
    }
  }
#pragma unroll
  for (int i = 0; i < 8; ++i) a[i] += __shfl_xor(a[i], 32, 64);

  if (hi == 0) {
    uint4v ov;
    ov.x = (unsigned int)f2bf(a[0]) | ((unsigned int)f2bf(a[1]) << 16);
    ov.y = (unsigned int)f2bf(a[2]) | ((unsigned int)f2bf(a[3]) << 16);
    ov.z = (unsigned int)f2bf(a[4]) | ((unsigned int)f2bf(a[5]) << 16);
    ov.w = (unsigned int)f2bf(a[6]) | ((unsigned int)f2bf(a[7]) << 16);
    *(uint4v*)(samp + (size_t)row * DM + m * 32 + q4 * 8) = ov;
  }
}

// ---------------------------------------------------------------------------
extern "C" void kernel_launch(void* const* d_in, const int* in_sizes, int n_in,
                              void* d_out, int out_size, void* d_ws, size_t ws_size,
                              hipStream_t stream)
{
  const float* src = (const float*)d_in[0];
  const float* pos = (const float*)d_in[1];
  const float* ref = (const float*)d_in[2];
  const float* all_vt = (const float*)d_in[6];
  const float* sel = (const float*)d_in[7];
  const float* Wv = (const float*)d_in[8];
  const float* bv = (const float*)d_in[9];
  const float* Wo = (const float*)d_in[10];
  const float* bo = (const float*)d_in[11];
  const float* Wa = (const float*)d_in[12];
  const float* ba = (const float*)d_in[13];
  const float* Wp = (const float*)d_in[14];
  const float* bp = (const float*)d_in[15];
  const float* g1 = (const float*)d_in[16];
  const float* be1 = (const float*)d_in[17];
  const float* W1 = (const float*)d_in[18];
  const float* b1 = (const float*)d_in[19];
  const float* W2 = (const float*)d_in[20];
  const float* b2 = (const float*)d_in[21];
  const float* g2 = (const float*)d_in[22];
  const float* be2 = (const float*)d_in[23];

  char* ws = (char*)d_ws;
  float* oabuf = (float*)(ws + OFF_R0);   // dead after sample4
  u16* h_bf    = (u16*)(ws + OFF_R0);     // written by ffn1 (after oa dead)
  u16* samp_bf = (u16*)(ws + OFF_R1);
  u16* x_bf    = (u16*)(ws + OFF_R2);
  u16* val_bf  = (u16*)(ws + OFF_R3);
  u16* WB      = (u16*)(ws + OFF_WB);
  float* boa   = (float*)(ws + OFF_BI);

  const dim3 b256(256);
  const int MT32 = (NR + 31) / 32;    // 681 (exact: 21792 = 32*681)

  // weights pack + [bo;ba] pack + all_vt passthrough (600 tail blocks)
  convw_k<<<dim3(NWELEM / 256 + 600), b256, 0, stream>>>(
      Wv, Wo, Wa, Wp, W1, W2, bo, ba, WB, boa,
      all_vt, (float*)d_out + OUT0);
  // FUSED: value = vin@Wv^T + bv  AND  [off|attn] = q@[Wo;Wa]^T + [bo;ba]
  headgemm_k<<<dim3(1, MT32), b256, 0, stream>>>(
      src, pos, sel, WB, bv, boa, val_bf, oabuf);
  // sampling (softmax fused), level-split across wave halves
  sample4_k<<<dim3(8 * 681), b256, 0, stream>>>(val_bf, oabuf, ref, samp_bf);
  // x = LN(v_in + samp @ Wp^T + bp) -> x_bf   (LN1 fused epilogue)
  gemmP<0, 2, 256, 1><<<dim3(1, MT32), b256, 0, stream>>>(
      samp_bf, 256, src, nullptr, sel, WB + WOF_P, 256, bp, 256,
      x_bf, 256, nullptr, g1, be1, nullptr, 0);
  // h = relu(x @ W1^T + b1)  N=1024 swept by NITER=4 inside the block
  gemmP<0, 1, 256, 4><<<dim3(1, MT32), b256, 0, stream>>>(
      x_bf, 256, nullptr, nullptr, nullptr, WB + WOF_1, 256, b1, 256,
      h_bf, 1024, nullptr, nullptr, nullptr, nullptr, 0);
  // out = LN(x + h @ W2^T + b2) scattered to d_out  (LN2 fused epilogue)
  gemmP<0, 3, 256, 1><<<dim3(1, MT32), b256, 0, stream>>>(
      h_bf, 1024, nullptr, nullptr, nullptr, WB + WOF_2, 1024, b2, 1024,
      nullptr, 0, x_bf, g2, be2, (float*)d_out, 0);
}